// Round 1
// baseline (803.832 us; speedup 1.0000x reference)
//
#include <hip/hip_runtime.h>

// HEALPix padding, specialized to the bench setup:
//   x: [B=1, F=12, C=128, H=256, W=256] float32, pad=1, channels_last=0
//   out: [1, 12, 128, 258, 258] float32
//
// One thread per output element. Interior (98.5% of elements) is a straight
// copy; the 1-px halo ring gathers from neighbor faces with the DLWP-HPX
// rotation conventions (derived from the JAX reference's rot90 compositions).

constexpr int H  = 256;
constexpr int W  = 256;
constexpr int P  = 1;
constexpr int HP = H + 2 * P;   // 258
constexpr int WP = W + 2 * P;   // 258
constexpr int C  = 128;
constexpr int IN_PLANE  = H * W;     // 65536
constexpr int OUT_PLANE = HP * WP;   // 66564

__global__ __launch_bounds__(256) void healpix_pad_kernel(
    const float* __restrict__ in, float* __restrict__ out, int total)
{
    int idx = blockIdx.x * blockDim.x + threadIdx.x;
    if (idx >= total) return;

    int n   = idx / OUT_PLANE;            // combined (b*12+f)*C + c index
    int rem = idx - n * OUT_PLANE;
    int y   = rem / WP;
    int x   = rem - y * WP;
    int face = n / C;                     // B == 1

    const long nbase = (long)n * IN_PLANE;
    // source offset base for neighbor face g (same batch & channel)
    auto foff = [&](int g) -> long {
        return nbase + (long)(g - face) * C * IN_PLANE;
    };

    float v;
    if (y >= P && y < P + H && x >= P && x < P + W) {
        // interior: plain copy
        v = in[nbase + (y - P) * W + (x - P)];
    } else {
        int ry = (y < P) ? 0 : (y < P + H ? 1 : 2);
        int rx = (x < P) ? 0 : (x < P + W ? 1 : 2);
        int my = y - P, mx = x - P;          // middle-region locals
        int ty = y,      tx = x;             // top/left-region locals [0,P)
        int by = y - P - H, bx = x - P - W;  // bottom/right-region locals [0,P)

        if (face < 4) {
            // -------- northern polar faces --------
            int i  = face;
            int t  = (i + 1) & 3;
            int tl = (i + 2) & 3;
            int l  = (i + 3) & 3;
            int bl = l;
            int b  = i + 4;
            int br = i + 8;
            int r  = 4 + ((i + 1) & 3);
            int tr = t;
            int g, yy, xx;
            if      (ry == 0 && rx == 1) { g = t;  yy = mx;          xx = P - 1 - ty; } // rot(t,1)[-p:,:]
            else if (ry == 2 && rx == 1) { g = b;  yy = by;          xx = mx;         }
            else if (ry == 0 && rx == 0) { g = tl; yy = P - 1 - ty;  xx = P - 1 - tx; } // rot(tl,2)
            else if (ry == 1 && rx == 0) { g = l;  yy = P - 1 - tx;  xx = my;         } // rot(l,-1)
            else if (ry == 2 && rx == 0) { g = bl; yy = by;          xx = W - P + tx; }
            else if (ry == 0 && rx == 2) { g = tr; yy = bx;          xx = P - 1 - ty; } // rot(tr,1)
            else if (ry == 1 && rx == 2) { g = r;  yy = my;          xx = bx;         }
            else                         { g = br; yy = by;          xx = bx;         }
            v = in[foff(g) + yy * W + xx];
        } else if (face < 8) {
            // -------- equatorial faces --------
            int i  = face - 4;
            int t  = i;
            int l  = (i + 3) & 3;
            int bl = 4 + ((i + 3) & 3);
            int b  = 8 + i;
            int r  = 8 + ((i + 3) & 3);
            int tr = 4 + ((i + 1) & 3);
            if      (ry == 0 && rx == 1) { v = in[foff(t)  + (H - P + ty) * W + mx]; }
            else if (ry == 2 && rx == 1) { v = in[foff(b)  + by * W + mx]; }
            else if (ry == 1 && rx == 0) { v = in[foff(l)  + my * W + (W - P + tx)]; }
            else if (ry == 2 && rx == 0) { v = in[foff(bl) + by * W + (W - P + tx)]; }
            else if (ry == 0 && rx == 2) { v = in[foff(tr) + (H - P + ty) * W + bx]; }
            else if (ry == 1 && rx == 2) { v = in[foff(r)  + my * W + bx]; }
            else if (ry == 0 && rx == 0) {
                // tl corner block (average point + continued edges for p>1)
                if      (ty == P - 1 && tx == P - 1)
                    v = 0.5f * in[foff(t) + (H - 1) * W + 0] +
                        0.5f * in[foff(l) + 0 * W + (W - 1)];
                else if (ty == P - 1) v = in[foff(l) + 0 * W + (W - P + tx)];
                else if (tx == P - 1) v = in[foff(t) + (H - P + ty) * W + 0];
                else                  v = 0.0f;
            } else {
                // br corner block
                if      (by == 0 && bx == 0)
                    v = 0.5f * in[foff(b) + 0 * W + (W - 1)] +
                        0.5f * in[foff(r) + (H - 1) * W + 0];
                else if (by == 0) v = in[foff(r) + (H - 1) * W + bx];
                else if (bx == 0) v = in[foff(b) + by * W + (W - 1)];
                else              v = 0.0f;
            }
        } else {
            // -------- southern polar faces --------
            int i  = face - 8;
            int t  = 4 + ((i + 1) & 3);
            int tl = i;
            int l  = 4 + i;
            int bl = 8 + ((i + 3) & 3);
            int b  = bl;
            int br = 8 + ((i + 2) & 3);
            int r  = 8 + ((i + 1) & 3);
            int tr = r;
            int g, yy, xx;
            if      (ry == 0 && rx == 1) { g = t;  yy = H - P + ty; xx = mx;         }
            else if (ry == 2 && rx == 1) { g = b;  yy = mx;         xx = W - 1 - by; } // rot(b,1)
            else if (ry == 0 && rx == 0) { g = tl; yy = H - P + ty; xx = W - P + tx; }
            else if (ry == 1 && rx == 0) { g = l;  yy = my;         xx = W - P + tx; }
            else if (ry == 2 && rx == 0) { g = bl; yy = W - P + tx; xx = W - 1 - by; } // rot(bl,1)
            else if (ry == 0 && rx == 2) { g = tr; yy = H - 1 - bx; xx = H - P + ty; } // rot(tr,-1)
            else if (ry == 1 && rx == 2) { g = r;  yy = H - 1 - bx; xx = my;         } // rot(r,-1)
            else                         { g = br; yy = H - 1 - by; xx = W - 1 - bx; } // rot(br,2)
            v = in[foff(g) + yy * W + xx];
        }
    }
    out[idx] = v;
}

extern "C" void kernel_launch(void* const* d_in, const int* in_sizes, int n_in,
                              void* d_out, int out_size, void* d_ws, size_t ws_size,
                              hipStream_t stream) {
    const float* in = (const float*)d_in[0];
    float* out = (float*)d_out;
    int total = out_size;                 // 12*128*258*258 = 102,242,304
    int threads = 256;
    int blocks = (total + threads - 1) / threads;
    healpix_pad_kernel<<<blocks, threads, 0, stream>>>(in, out, total);
}